// Round 1
// baseline (7709.947 us; speedup 1.0000x reference)
//
#include <hip/hip_runtime.h>
#include <type_traits>

// ---------------- types ----------------
typedef _Float16 half8 __attribute__((ext_vector_type(8)));
typedef _Float16 half4v __attribute__((ext_vector_type(4)));
typedef float f32x4 __attribute__((ext_vector_type(4)));

struct U128 { unsigned long long a, b; };

#define B_ 64
#define T_ 512
#define H_ 1024
#define G_ 4096      // 4*H
#define K_ 1024
#define MPROJ (B_ * T_)  // 32768

// ---------------- prep kernels ----------------
__global__ void k_f32_to_f16(const float* __restrict__ s, _Float16* __restrict__ d, int n4) {
  int i = blockIdx.x * 256 + threadIdx.x;
  if (i < n4) {
    float4 v = ((const float4*)s)[i];
    half4v o;
    o[0] = (_Float16)v.x; o[1] = (_Float16)v.y; o[2] = (_Float16)v.z; o[3] = (_Float16)v.w;
    ((half4v*)d)[i] = o;
  }
}

__global__ void k_bias(const float* __restrict__ bi0, const float* __restrict__ bh0,
                       const float* __restrict__ bi1, const float* __restrict__ bh1,
                       float* __restrict__ o0, float* __restrict__ o1) {
  int i = blockIdx.x * 256 + threadIdx.x;
  if (i < G_) { o0[i] = bi0[i] + bh0[i]; o1[i] = bi1[i] + bh1[i]; }
}

__global__ void k_zero(uint4* __restrict__ p, int n) {
  int i = blockIdx.x * 256 + threadIdx.x;
  if (i < n) p[i] = make_uint4(0u, 0u, 0u, 0u);
}

// ---------------- projection GEMM ----------------
// C[m][n] = sum_k A[m][k]*Bw[n][k] + bias[n], C stored fp16. M=32768, N=4096, K=1024.
// 128x128 tile, BK=32, 256 thr (4 waves, each a 64x64 quadrant of 4x4 16x16x32 MFMAs).
template <typename AT>
__global__ __launch_bounds__(256, 2) void k_proj(const AT* __restrict__ A,
                                                 const _Float16* __restrict__ Bw,
                                                 const float* __restrict__ bias,
                                                 _Float16* __restrict__ C) {
  const int NBN = G_ / 128;  // 32
  int bm = blockIdx.x / NBN;
  int bn = blockIdx.x % NBN;
  __shared__ __align__(16) _Float16 As[128 * 40];
  __shared__ __align__(16) _Float16 Bs[128 * 40];
  int tid = threadIdx.x;
  int lane = tid & 63, wave = tid >> 6;
  int wm = (wave >> 1) * 64, wn = (wave & 1) * 64;
  int quad = lane >> 4, l16 = lane & 15;
  f32x4 acc[4][4] = {};
  int r = tid >> 1;            // staged row 0..127
  int hc = (tid & 1) * 16;     // half-offset within BK=32
  const AT* aRow = A + (size_t)(bm * 128 + r) * K_ + hc;
  const _Float16* bRow = Bw + (size_t)(bn * 128 + r) * K_ + hc;
  _Float16* aDst = As + r * 40 + hc;
  _Float16* bDst = Bs + r * 40 + hc;

  for (int kt = 0; kt < K_ / 32; ++kt) {
    if constexpr (std::is_same<AT, float>::value) {
      float tmp[16];
      *(float4*)(tmp + 0)  = *(const float4*)(aRow + 0);
      *(float4*)(tmp + 4)  = *(const float4*)(aRow + 4);
      *(float4*)(tmp + 8)  = *(const float4*)(aRow + 8);
      *(float4*)(tmp + 12) = *(const float4*)(aRow + 12);
      half8 h0, h1;
#pragma unroll
      for (int e = 0; e < 8; ++e) { h0[e] = (_Float16)tmp[e]; h1[e] = (_Float16)tmp[e + 8]; }
      *(half8*)(aDst) = h0;
      *(half8*)(aDst + 8) = h1;
    } else {
      *(half8*)(aDst) = *(const half8*)(aRow);
      *(half8*)(aDst + 8) = *(const half8*)(aRow + 8);
    }
    *(half8*)(bDst) = *(const half8*)(bRow);
    *(half8*)(bDst + 8) = *(const half8*)(bRow + 8);
    __syncthreads();
    half8 af[4], bf[4];
#pragma unroll
    for (int i = 0; i < 4; ++i) af[i] = *(const half8*)(As + (wm + i * 16 + l16) * 40 + quad * 8);
#pragma unroll
    for (int j = 0; j < 4; ++j) bf[j] = *(const half8*)(Bs + (wn + j * 16 + l16) * 40 + quad * 8);
#pragma unroll
    for (int i = 0; i < 4; ++i)
#pragma unroll
      for (int j = 0; j < 4; ++j)
        acc[i][j] = __builtin_amdgcn_mfma_f32_16x16x32_f16(af[i], bf[j], acc[i][j], 0, 0, 0);
    __syncthreads();
    aRow += 32;
    bRow += 32;
  }
  // epilogue: C/D layout m = quad*4+reg, n = lane&15
#pragma unroll
  for (int j = 0; j < 4; ++j) {
    int n = bn * 128 + wn + j * 16 + l16;
    float bv = bias[n];
#pragma unroll
    for (int i = 0; i < 4; ++i) {
      size_t m0 = (size_t)(bm * 128 + wm + i * 16 + quad * 4);
#pragma unroll
      for (int rr = 0; rr < 4; ++rr)
        C[(m0 + rr) * G_ + n] = (_Float16)(acc[i][j][rr] + bv);
    }
  }
}

// ---------------- persistent recurrence ----------------
// 256 WGs x 512 thr (cooperative). Group g = blockIdx&3 owns batch rows [16g,16g+16),
// WG wid = blockIdx>>2 owns hidden units [16*wid,16*wid+16) (all 4 gates).
// W_hh slice in registers (K split 8-ways over waves). c state in LDS.
//
// Sync protocol (v2): NO central counter, NO atomic RMW, NO LDS relay.
//  - flags layout: per layer, [4 groups][64 wid][4 producer-wave] uints, monotonic = step+1.
//  - producer wave w<4 stores its 4 h-rows (agent sc1), inline `s_waitcnt vmcnt(0)`
//    (counts ONLY h stores: out/hn/cn stores are issued AFTER), then lane0 plain-stores
//    its flag. Single writer per flag -> no RMW serialization at the coherence point.
//  - consumer wave w polls only the 32 flags of its 8 K-slice producers
//    (wid' in [8w,8w+8), 4 waves each = 128 contiguous bytes), then loads h.
//    Waves proceed independently; h-load latency overlaps straggler publishes.
//  - ping-pong safety: WG publishes step s only after sync#2, i.e. after all 8 of its
//    waves (producer sets union = all 64 WGs) observed flags >= s -> every read of the
//    buffer being overwritten has completed.
__global__ __launch_bounds__(512, 2) void k_rec(
    const _Float16* __restrict__ xg,   // [B*T][4H] fp16, includes both biases
    const _Float16* __restrict__ Whh,  // [4H][H] fp16
    _Float16* __restrict__ hb0, _Float16* __restrict__ hb1,  // [B][H] ping-pong
    unsigned int* flags,               // per-layer flag base (see above)
    _Float16* __restrict__ out16,      // layer0: out0 buffer; layer1: null
    float* __restrict__ out32,         // layer1: d_out; layer0: null
    float* __restrict__ hn_out, float* __restrict__ cn_out) {
  int g = blockIdx.x & 3;
  int wid = blockIdx.x >> 2;
  int u0 = wid * 16;
  int b0 = g * 16;
  int tid = threadIdx.x;
  int lane = tid & 63, w = tid >> 6;
  int quad = lane >> 4, l16 = lane & 15;

  // m-stride padded to 18 floats: all access phases are <=2-way bank aliased (free)
  __shared__ float part[8][4][16][18];  // [wave][gate][m][n]
  __shared__ float red[4][16][18];      // reduced gates
  __shared__ float cs[16][16];          // cell state
  if (tid < 256) ((float*)cs)[tid] = 0.f;

  unsigned int* gflags = flags + (g << 8);          // 256 uints per group
  unsigned int* myflg  = gflags + wid * 4;          // + w = this wave's flag
  unsigned int* pollp  = gflags + w * 32 + lane;    // lane<32: producer (8w+lane>>2, lane&3)

  // resident W_hh fragments: wave w covers K-slice [128w, 128w+128)
  int ks = w * 128;
  half8 wf[4][4];
#pragma unroll
  for (int gt = 0; gt < 4; ++gt)
#pragma unroll
    for (int kk = 0; kk < 4; ++kk)
      wf[gt][kk] = *(const half8*)(Whh + (size_t)(gt * H_ + u0 + l16) * K_ + ks + kk * 32 + quad * 8);
  int fm = (w & 3) * 4 + quad;
  __syncthreads();

  for (int s = 0; s < T_; ++s) {
    const _Float16* hp = (s & 1) ? hb1 : hb0;
    _Float16* hnx = (s & 1) ? hb0 : hb1;

    // xg prefetch issued BEFORE the poll: HBM latency hides under the spin
    float pxi = 0.f, pxf = 0.f, pxg = 0.f, pxo = 0.f;
    if (w < 4) {
      const _Float16* xr = xg + ((size_t)(b0 + fm) * T_ + s) * G_ + u0 + l16;
      pxi = (float)xr[0];
      pxf = (float)xr[H_];
      pxg = (float)xr[2 * H_];
      pxo = (float)xr[3 * H_];
    }

    // fine-grained poll: this wave's 8 producers x 4 waves (2 cache lines)
    if (s > 0 && lane < 32) {
      while (__hip_atomic_load(pollp, __ATOMIC_RELAXED, __HIP_MEMORY_SCOPE_AGENT) < (unsigned)s)
        __builtin_amdgcn_s_sleep(1);
    }
    asm volatile("" ::: "memory");  // no h load hoisted above the poll

    // batch-issue all 8 h loads, then MFMA
    half8 af[4];
#pragma unroll
    for (int kk = 0; kk < 4; ++kk) {
      const _Float16* hsrc = hp + (size_t)(b0 + l16) * H_ + ks + kk * 32 + quad * 8;
      unsigned long long qlo = __hip_atomic_load((unsigned long long*)hsrc,
                                                 __ATOMIC_RELAXED, __HIP_MEMORY_SCOPE_AGENT);
      unsigned long long qhi = __hip_atomic_load(((unsigned long long*)hsrc) + 1,
                                                 __ATOMIC_RELAXED, __HIP_MEMORY_SCOPE_AGENT);
      U128 u; u.a = qlo; u.b = qhi;
      af[kk] = __builtin_bit_cast(half8, u);
    }
    f32x4 acc[4] = {};
#pragma unroll
    for (int kk = 0; kk < 4; ++kk)
#pragma unroll
      for (int gt = 0; gt < 4; ++gt)
        acc[gt] = __builtin_amdgcn_mfma_f32_16x16x32_f16(af[kk], wf[gt][kk], acc[gt], 0, 0, 0);
#pragma unroll
    for (int gt = 0; gt < 4; ++gt)
#pragma unroll
      for (int rr = 0; rr < 4; ++rr)
        part[w][gt][quad * 4 + rr][l16] = acc[gt][rr];
    __syncthreads();  // sync#1: join for reduce

    {  // cross-wave K reduction: wave w -> gate w&3, row-half w>>2
      int gt = w & 3, rh = w >> 2;
#pragma unroll
      for (int rr = 2 * rh; rr < 2 * rh + 2; ++rr) {
        int m = quad * 4 + rr;
        float sum = part[0][gt][m][l16];
#pragma unroll
        for (int w2 = 1; w2 < 8; ++w2) sum += part[w2][gt][m][l16];
        red[gt][m][l16] = sum;
      }
    }
    __syncthreads();  // sync#2: red ready; all waves' h reads for this step complete

    if (w < 4) {  // finalization: 4 waves x 64 lanes = 256 (m,n) cells
      int m = fm, n = l16;
      float iv = red[0][m][n] + pxi;
      float fv = red[1][m][n] + pxf;
      float gv = red[2][m][n] + pxg;
      float ov = red[3][m][n] + pxo;
      float si = 1.f / (1.f + __expf(-iv));
      float sf = 1.f / (1.f + __expf(-fv));
      float so = 1.f / (1.f + __expf(-ov));
      float ag = fabsf(gv), eg = __expf(-2.f * ag);
      float tg = (1.f - eg) / (1.f + eg);
      tg = (gv < 0.f) ? -tg : tg;
      float c = sf * cs[m][n] + si * tg;
      float ac = fabsf(c), ec = __expf(-2.f * ac);
      float th = (1.f - ec) / (1.f + ec);
      th = (c < 0.f) ? -th : th;
      float h = so * th;
      // h ping-pong store: packed 2xfp16, agent-coherent
      unsigned short hu = __builtin_bit_cast(unsigned short, (_Float16)h);
      unsigned other = __shfl_xor((unsigned)hu, 1, 64);
      if ((l16 & 1) == 0) {
        unsigned packed = (unsigned)hu | (other << 16);
        __hip_atomic_store((unsigned*)(hnx + (size_t)(b0 + m) * H_ + u0 + l16), packed,
                           __ATOMIC_RELAXED, __HIP_MEMORY_SCOPE_AGENT);
      }
      // drain ONLY the h stores (out stores not yet issued), then publish
      asm volatile("s_waitcnt vmcnt(0)" ::: "memory");
      if (lane == 0)
        __hip_atomic_store(myflg + w, (unsigned)(s + 1),
                           __ATOMIC_RELAXED, __HIP_MEMORY_SCOPE_AGENT);
      // ---- off the critical path ----
      cs[m][n] = c;
      size_t oidx = ((size_t)(b0 + m) * T_ + s) * H_ + u0 + n;
      if (out16) out16[oidx] = (_Float16)h;
      if (out32) out32[oidx] = h;
      if (s == T_ - 1) {
        hn_out[(size_t)(b0 + m) * H_ + u0 + n] = h;
        cn_out[(size_t)(b0 + m) * H_ + u0 + n] = c;
      }
    }
    // no third barrier: waves 4-7 run ahead into the next round's poll;
    // part[] reuse is protected by sync#2 (this step) + sync#1 (next step).
  }
}

// ---------------- host ----------------
extern "C" void kernel_launch(void* const* d_in, const int* in_sizes, int n_in,
                              void* d_out, int out_size, void* d_ws, size_t ws_size,
                              hipStream_t stream) {
  (void)in_sizes; (void)n_in; (void)out_size;
  const float* X    = (const float*)d_in[0];
  const float* Wih0 = (const float*)d_in[1];
  const float* bih0 = (const float*)d_in[2];
  const float* Whh0 = (const float*)d_in[3];
  const float* bhh0 = (const float*)d_in[4];
  const float* Wih1 = (const float*)d_in[5];
  const float* bih1 = (const float*)d_in[6];
  const float* Whh1 = (const float*)d_in[7];
  const float* bhh1 = (const float*)d_in[8];
  float* out = (float*)d_out;
  char* ws = (char*)d_ws;

  // ws layout (bytes):
  constexpr size_t SZW = (size_t)G_ * K_ * 2;  // 8 MB per packed weight
  constexpr size_t OFF_B0   = 4 * SZW;
  constexpr size_t OFF_B1   = OFF_B0 + 16384;
  constexpr size_t OFF_CNT  = OFF_B1 + 16384;          // flags: 2 layers x 4KB (16KB reserved)
  constexpr size_t OFF_HBUF = OFF_CNT + 16384;
  constexpr size_t OFF_OUT0 = OFF_HBUF + 4 * 131072;
  constexpr size_t OFF_XG   = OFF_OUT0 + (size_t)MPROJ * H_ * 2;
  constexpr size_t NEED     = OFF_XG + (size_t)MPROJ * G_ * 2;
  if (ws_size < NEED) return;  // fail visibly rather than corrupt

  _Float16* Wih0h = (_Float16*)(ws + 0 * SZW);
  _Float16* Whh0h = (_Float16*)(ws + 1 * SZW);
  _Float16* Wih1h = (_Float16*)(ws + 2 * SZW);
  _Float16* Whh1h = (_Float16*)(ws + 3 * SZW);
  float* b0s = (float*)(ws + OFF_B0);
  float* b1s = (float*)(ws + OFF_B1);
  unsigned int* cnts = (unsigned int*)(ws + OFF_CNT);
  _Float16* hbase = (_Float16*)(ws + OFF_HBUF);
  _Float16* hb00 = hbase;
  _Float16* hb01 = hbase + 65536;
  _Float16* hb10 = hbase + 131072;
  _Float16* hb11 = hbase + 196608;
  _Float16* out0h = (_Float16*)(ws + OFF_OUT0);
  _Float16* xgp   = (_Float16*)(ws + OFF_XG);

  // prep: pack weights to fp16, fold biases, zero h/flags
  k_f32_to_f16<<<4096, 256, 0, stream>>>(Wih0, Wih0h, G_ * K_ / 4);
  k_f32_to_f16<<<4096, 256, 0, stream>>>(Whh0, Whh0h, G_ * K_ / 4);
  k_f32_to_f16<<<4096, 256, 0, stream>>>(Wih1, Wih1h, G_ * K_ / 4);
  k_f32_to_f16<<<4096, 256, 0, stream>>>(Whh1, Whh1h, G_ * K_ / 4);
  k_bias<<<16, 256, 0, stream>>>(bih0, bhh0, bih1, bhh1, b0s, b1s);
  k_zero<<<132, 256, 0, stream>>>((uint4*)(ws + OFF_CNT), (16384 + 4 * 131072) / 16);

  const int projGrid = (MPROJ / 128) * (G_ / 128);  // 8192

  // layer 0
  k_proj<float><<<dim3(projGrid), dim3(256), 0, stream>>>(X, Wih0h, b0s, xgp);
  {
    const _Float16* a0 = xgp;
    const _Float16* a1 = Whh0h;
    _Float16* a2 = hb00;
    _Float16* a3 = hb01;
    unsigned int* a4 = cnts;               // layer0 flags
    _Float16* a5 = out0h;
    float* a6 = nullptr;
    float* a7 = out + 33554432;            // h_n[0]
    float* a8 = out + 33554432 + 131072;   // c_n[0]
    void* args[9] = {&a0, &a1, &a2, &a3, &a4, &a5, &a6, &a7, &a8};
    hipLaunchCooperativeKernel((void*)k_rec, dim3(256), dim3(512), args, 0, stream);
  }

  // layer 1
  k_proj<_Float16><<<dim3(projGrid), dim3(256), 0, stream>>>(out0h, Wih1h, b1s, xgp);
  {
    const _Float16* a0 = xgp;
    const _Float16* a1 = Whh1h;
    _Float16* a2 = hb10;
    _Float16* a3 = hb11;
    unsigned int* a4 = cnts + 1024;        // layer1 flags (+4KB)
    _Float16* a5 = nullptr;
    float* a6 = out;                               // out1
    float* a7 = out + 33554432 + 65536;            // h_n[1]
    float* a8 = out + 33554432 + 131072 + 65536;   // c_n[1]
    void* args[9] = {&a0, &a1, &a2, &a3, &a4, &a5, &a6, &a7, &a8};
    hipLaunchCooperativeKernel((void*)k_rec, dim3(256), dim3(512), args, 0, stream);
  }
}